// Round 8
// baseline (874.555 us; speedup 1.0000x reference)
//
#include <hip/hip_runtime.h>
#include <hip/hip_bf16.h>

#define DEV __device__ __forceinline__

static DEV float lrelu(float v) { return v >= 0.f ? v : 0.01f * v; }

constexpr int BATCH = 256;

// ---- compact workspace layout (bytes) -- total 20,447,232 B ----
// A: [0, 13107200)        p1 (bf16) -> later h5 (bf16)
// B: [13107200, 18350080) p2 (f32)  -> later h4 (f32)
// C: [18350080, 19398656) p3 (f32)
// D: [19398656, 20447232) dec (f32)
constexpr size_t BYTE_B = 13107200;
constexpr size_t BYTE_C = 18350080;
constexpr size_t BYTE_D = 19398656;

// ---------------------------------------------------------------- k1
// conv1 (6->8, 3x3 SAME) + lrelu + maxpool 2x2 : x(256,6,100,128) -> p1(256,8,50,64) bf16
__global__ __launch_bounds__(256) void k1_conv1_pool(
    const float* __restrict__ x, const float* __restrict__ w1,
    const float* __restrict__ b1, __hip_bfloat16* __restrict__ p1) {
  __shared__ float xs[6][12][130];
  __shared__ float wsh[432];
  __shared__ float bsh[8];
  const int b = blockIdx.x, yt = blockIdx.y, tid = threadIdx.x;
  for (int i = tid; i < 432; i += 256) wsh[i] = w1[i];
  if (tid < 8) bsh[tid] = b1[tid];
  for (int i = tid; i < 6 * 12 * 130; i += 256) {
    int col = i % 130, rem = i / 130, r = rem % 12, c = rem / 12;
    int gy = 10 * yt + r - 1, gx = col - 1;
    float v = 0.f;
    if (gy >= 0 && gy < 100 && (unsigned)gx < 128u)
      v = x[((b * 6 + c) * 100 + gy) * 128 + gx];
    xs[c][r][col] = v;
  }
  __syncthreads();
  for (int i = tid; i < 2560; i += 256) {
    int ox = i & 63, rem = i >> 6, oy = rem % 5, co = rem / 5;
    float m = -1e30f;
    #pragma unroll
    for (int dy = 0; dy < 2; ++dy)
      #pragma unroll
      for (int dx = 0; dx < 2; ++dx) {
        int cy = 2 * oy + dy, cx = 2 * ox + dx;
        float acc = bsh[co];
        #pragma unroll
        for (int ci = 0; ci < 6; ++ci)
          #pragma unroll
          for (int ky = 0; ky < 3; ++ky)
            #pragma unroll
            for (int kx = 0; kx < 3; ++kx)
              acc += xs[ci][cy + ky][cx + kx] * wsh[(co * 6 + ci) * 9 + ky * 3 + kx];
        m = fmaxf(m, lrelu(acc));
      }
    p1[((b * 8 + co) * 50 + 5 * yt + oy) * 64 + ox] = __float2bfloat16(m);
  }
}

// ---------------------------------------------------------------- k2
// conv2 (8->16) + lrelu + maxpool 5x2 : p1(bf16) -> p2(256,16,10,32) f32
__global__ __launch_bounds__(256) void k2_conv2_pool(
    const __hip_bfloat16* __restrict__ p1, const float* __restrict__ w2,
    const float* __restrict__ b2, float* __restrict__ p2) {
  __shared__ float s1[8][7][66];
  __shared__ float wsh[1152];
  __shared__ float bsh[16];
  const int b = blockIdx.x, yt = blockIdx.y, tid = threadIdx.x;
  for (int i = tid; i < 1152; i += 256) wsh[i] = w2[i];
  if (tid < 16) bsh[tid] = b2[tid];
  for (int i = tid; i < 8 * 7 * 66; i += 256) {
    int col = i % 66, rem = i / 66, r = rem % 7, c = rem / 7;
    int gy = 5 * yt + r - 1, gx = col - 1;
    float v = 0.f;
    if (gy >= 0 && gy < 50 && (unsigned)gx < 64u)
      v = __bfloat162float(p1[((b * 8 + c) * 50 + gy) * 64 + gx]);
    s1[c][r][col] = v;
  }
  __syncthreads();
  for (int i = tid; i < 512; i += 256) {
    int ox = i & 31, co = i >> 5;
    float m = -1e30f;
    for (int dy = 0; dy < 5; ++dy)
      #pragma unroll
      for (int dx = 0; dx < 2; ++dx) {
        int cx = 2 * ox + dx;
        float acc = bsh[co];
        #pragma unroll
        for (int ci = 0; ci < 8; ++ci)
          #pragma unroll
          for (int ky = 0; ky < 3; ++ky)
            #pragma unroll
            for (int kx = 0; kx < 3; ++kx)
              acc += s1[ci][dy + ky][cx + kx] * wsh[(co * 8 + ci) * 9 + ky * 3 + kx];
        m = fmaxf(m, lrelu(acc));
      }
    p2[((b * 16 + co) * 10 + yt) * 32 + ox] = m;
  }
}

// ---------------------------------------------------------------- k3
// conv3 (16->32) + lrelu + maxpool 5x2 : p2 -> p3(256,32,2,16) f32
__global__ __launch_bounds__(256) void k3_conv3_pool(
    const float* __restrict__ p2, const float* __restrict__ w3,
    const float* __restrict__ b3, float* __restrict__ p3) {
  __shared__ float s2[16][12][34];
  __shared__ float wsh[4608];
  __shared__ float bsh[32];
  const int b = blockIdx.x, tid = threadIdx.x;
  for (int i = tid; i < 4608; i += 256) wsh[i] = w3[i];
  if (tid < 32) bsh[tid] = b3[tid];
  for (int i = tid; i < 16 * 12 * 34; i += 256) {
    int col = i % 34, rem = i / 34, r = rem % 12, c = rem / 12;
    int gy = r - 1, gx = col - 1;
    float v = 0.f;
    if ((unsigned)gy < 10u && (unsigned)gx < 32u)
      v = p2[((b * 16 + c) * 10 + gy) * 32 + gx];
    s2[c][r][col] = v;
  }
  __syncthreads();
  for (int i = tid; i < 1024; i += 256) {
    int ow = i & 15, rem = i >> 4, oh = rem & 1, co = rem >> 1;
    float m = -1e30f;
    for (int dy = 0; dy < 5; ++dy)
      #pragma unroll
      for (int dx = 0; dx < 2; ++dx) {
        int cy = 5 * oh + dy, cx = 2 * ow + dx;
        float acc = bsh[co];
        #pragma unroll
        for (int ci = 0; ci < 16; ++ci)
          #pragma unroll
          for (int ky = 0; ky < 3; ++ky)
            #pragma unroll
            for (int kx = 0; kx < 3; ++kx)
              acc += s2[ci][cy + ky][cx + kx] * wsh[(co * 16 + ci) * 9 + ky * 3 + kx];
        m = fmaxf(m, lrelu(acc));
      }
    p3[((b * 32 + co) * 2 + oh) * 16 + ow] = m;
  }
}

// ---------------------------------------------------------------- k4
// latent: mu/logvar/z/kld (ALL f32 -> out) + dec = z@wlin+blin (f32 ws)
__global__ __launch_bounds__(64) void k4_latent(
    const float* __restrict__ p3, const float* __restrict__ eps,
    const float* __restrict__ wmu, const float* __restrict__ bmu,
    const float* __restrict__ wlv, const float* __restrict__ blv,
    const float* __restrict__ wlin, const float* __restrict__ blin,
    float* __restrict__ dec, float* __restrict__ out,
    size_t off_mu, size_t off_lv, size_t off_kld, size_t off_z) {
  const int b = blockIdx.x, t = threadIdx.x;
  __shared__ float skld[32];
  if (t < 32) {
    const int h = t >> 4, w = t & 15;
    float f[32];
    #pragma unroll
    for (int c = 0; c < 32; ++c) f[c] = p3[((b * 32 + c) * 2 + h) * 16 + w];
    const int n = b * 32 + t;
    float mu[4], lv[4], zz[4];
    #pragma unroll
    for (int j = 0; j < 4; ++j) {
      float m = bmu[j], l = blv[j];
      #pragma unroll
      for (int c = 0; c < 32; ++c) { m += f[c] * wmu[c * 4 + j]; l += f[c] * wlv[c * 4 + j]; }
      mu[j] = m; lv[j] = l;
      zz[j] = m + eps[n * 4 + j] * expf(0.5f * l);
    }
    float kc = 0.f;
    #pragma unroll
    for (int j = 0; j < 4; ++j) kc += 1.f + lv[j] - mu[j] * mu[j] - expf(lv[j]);
    skld[t] = -0.5f * kc;
    #pragma unroll
    for (int j = 0; j < 4; ++j) {
      out[off_mu + n * 4 + j] = mu[j];
      out[off_lv + n * 4 + j] = lv[j];
      out[off_z  + n * 4 + j] = zz[j];
    }
    for (int co = 0; co < 32; ++co) {
      float d = blin[co];
      #pragma unroll
      for (int j = 0; j < 4; ++j) d += zz[j] * wlin[j * 32 + co];
      dec[((b * 32 + co) * 2 + h) * 16 + w] = d;
    }
  }
  __syncthreads();
  if (t == 0) {
    float s = 0.f;
    for (int i = 0; i < 32; ++i) s += skld[i];
    out[off_kld + b] = s * (1.f / 32.f);
  }
}

// ---------------------------------------------------------------- k5
// invconv1(32->32,5x2)+lrelu (LDS) then conv4(32->16)+lrelu : dec -> h4 f32
__global__ __launch_bounds__(256) void k5_inv1_conv4(
    const float* __restrict__ dec, const float* __restrict__ wi1,
    const float* __restrict__ bi1, const float* __restrict__ w4,
    const float* __restrict__ b4, float* __restrict__ h4) {
  __shared__ float sdec[1024];
  __shared__ float su1[32][12][34];
  const int b = blockIdx.x, tid = threadIdx.x;
  for (int i = tid; i < 1024; i += 256) sdec[i] = dec[b * 1024 + i];
  for (int i = tid; i < 32 * 12 * 34; i += 256) ((float*)su1)[i] = 0.f;
  __syncthreads();
  for (int i = tid; i < 32 * 10 * 32; i += 256) {
    int X = i & 31, rem = i >> 5, Y = rem % 10, c = rem / 10;
    int hh = Y / 5, ky = Y % 5, wp = X >> 1, kx = X & 1;
    float acc = bi1[c];
    #pragma unroll
    for (int ci = 0; ci < 32; ++ci)
      acc += sdec[(ci * 2 + hh) * 16 + wp] * wi1[((ci * 32 + c) * 5 + ky) * 2 + kx];
    su1[c][Y + 1][X + 1] = lrelu(acc);
  }
  __syncthreads();
  for (int i = tid; i < 16 * 10 * 32; i += 256) {
    int X = i & 31, rem = i >> 5, Y = rem % 10, o = rem / 10;
    float acc = b4[o];
    for (int c = 0; c < 32; ++c)
      #pragma unroll
      for (int ky = 0; ky < 3; ++ky)
        #pragma unroll
        for (int kx = 0; kx < 3; ++kx)
          acc += su1[c][Y + ky][X + kx] * w4[((o * 32 + c) * 3 + ky) * 3 + kx];
    h4[((b * 16 + o) * 10 + Y) * 32 + X] = lrelu(acc);
  }
}

// ---------------------------------------------------------------- k6
// invconv2(16->16,5x2)+lrelu (LDS tile) then conv5(16->8)+lrelu : h4 -> h5 bf16
__global__ __launch_bounds__(256) void k6_inv2_conv5(
    const float* __restrict__ h4, const float* __restrict__ wi2,
    const float* __restrict__ bi2, const float* __restrict__ w5,
    const float* __restrict__ b5, __hip_bfloat16* __restrict__ h5) {
  __shared__ float su2[16][12][66];
  __shared__ float sh4[16][4][32];
  const int b = blockIdx.x, yt = blockIdx.y, tid = threadIdx.x;
  const int y0 = 10 * yt;
  const int r0 = (y0 == 0) ? 0 : (y0 - 1) / 5;
  for (int i = tid; i < 16 * 4 * 32; i += 256) {
    int xx = i & 31, rem = i >> 5, r = rem & 3, c = rem >> 2;
    int gr = r0 + r;
    sh4[c][r][xx] = (gr < 10) ? h4[((b * 16 + c) * 10 + gr) * 32 + xx] : 0.f;
  }
  __syncthreads();
  for (int i = tid; i < 16 * 12 * 66; i += 256) {
    int lx = i % 66, rem = i / 66, ly = rem % 12, c = rem / 12;
    int Y = y0 - 1 + ly, X = lx - 1;
    float v = 0.f;
    if ((unsigned)Y < 50u && (unsigned)X < 64u) {
      int hr = Y / 5 - r0, ky = Y % 5, hc = X >> 1, kx = X & 1;
      float acc = bi2[c];
      #pragma unroll
      for (int ci = 0; ci < 16; ++ci)
        acc += sh4[ci][hr][hc] * wi2[((ci * 16 + c) * 5 + ky) * 2 + kx];
      v = lrelu(acc);
    }
    su2[c][ly][lx] = v;
  }
  __syncthreads();
  for (int i = tid; i < 8 * 10 * 64; i += 256) {
    int X = i & 63, rem = i >> 6, Y = rem % 10, o = rem / 10;
    float acc = b5[o];
    for (int c = 0; c < 16; ++c)
      #pragma unroll
      for (int ky = 0; ky < 3; ++ky)
        #pragma unroll
        for (int kx = 0; kx < 3; ++kx)
          acc += su2[c][Y + ky][X + kx] * w5[((o * 16 + c) * 3 + ky) * 3 + kx];
    h5[((b * 8 + o) * 50 + y0 + Y) * 64 + X] = __float2bfloat16(lrelu(acc));
  }
}

// ---------------------------------------------------------------- k7
// invconv3(8->8,2x2)+lrelu (LDS tile) then conv6(8->6, no act) : h5(bf16) -> out f32
__global__ __launch_bounds__(256) void k7_inv3_conv6(
    const __hip_bfloat16* __restrict__ h5, const float* __restrict__ wi3,
    const float* __restrict__ bi3, const float* __restrict__ w6,
    const float* __restrict__ b6, float* __restrict__ out) {
  __shared__ float su3[8][12][130];
  const int b = blockIdx.x, yt = blockIdx.y, tid = threadIdx.x;
  const int y0 = 10 * yt;
  for (int i = tid; i < 8 * 12 * 130; i += 256) {
    int lx = i % 130, rem = i / 130, ly = rem % 12, c = rem / 12;
    int Y = y0 - 1 + ly, X = lx - 1;
    float v = 0.f;
    if ((unsigned)Y < 100u && (unsigned)X < 128u) {
      int hr = Y >> 1, ky = Y & 1, hc = X >> 1, kx = X & 1;
      float acc = bi3[c];
      #pragma unroll
      for (int ci = 0; ci < 8; ++ci)
        acc += __bfloat162float(h5[((b * 8 + ci) * 50 + hr) * 64 + hc]) *
               wi3[((ci * 8 + c) * 2 + ky) * 2 + kx];
      v = lrelu(acc);
    }
    su3[c][ly][lx] = v;
  }
  __syncthreads();
  for (int i = tid; i < 6 * 10 * 128; i += 256) {
    int X = i & 127, rem = i >> 7, Y = rem % 10, o = rem / 10;
    float acc = b6[o];
    for (int c = 0; c < 8; ++c)
      #pragma unroll
      for (int ky = 0; ky < 3; ++ky)
        #pragma unroll
        for (int kx = 0; kx < 3; ++kx)
          acc += su3[c][Y + ky][X + kx] * w6[((o * 8 + c) * 3 + ky) * 3 + kx];
    out[((b * 6 + o) * 100 + y0 + Y) * 128 + X] = acc;
  }
}

// ---------------------------------------------------------------- launch
extern "C" void kernel_launch(void* const* d_in, const int* in_sizes, int n_in,
                              void* d_out, int out_size, void* d_ws, size_t ws_size,
                              hipStream_t stream) {
  const float* x    = (const float*)d_in[0];
  const float* eps  = (const float*)d_in[1];
  const float* w1   = (const float*)d_in[2];
  const float* b1   = (const float*)d_in[3];
  const float* w2   = (const float*)d_in[4];
  const float* b2   = (const float*)d_in[5];
  const float* w3   = (const float*)d_in[6];
  const float* b3   = (const float*)d_in[7];
  const float* wmu  = (const float*)d_in[8];
  const float* bmu  = (const float*)d_in[9];
  const float* wlv  = (const float*)d_in[10];
  const float* blv  = (const float*)d_in[11];
  const float* wlin = (const float*)d_in[12];
  const float* blin = (const float*)d_in[13];
  const float* wi1  = (const float*)d_in[14];
  const float* bi1  = (const float*)d_in[15];
  const float* w4   = (const float*)d_in[16];
  const float* b4   = (const float*)d_in[17];
  const float* wi2  = (const float*)d_in[18];
  const float* bi2  = (const float*)d_in[19];
  const float* w5   = (const float*)d_in[20];
  const float* b5   = (const float*)d_in[21];
  const float* wi3  = (const float*)d_in[22];
  const float* bi3  = (const float*)d_in[23];
  const float* w6   = (const float*)d_in[24];
  const float* b6   = (const float*)d_in[25];

  char* wsb = (char*)d_ws;
  __hip_bfloat16* p1 = (__hip_bfloat16*)wsb;          // region A
  __hip_bfloat16* h5 = (__hip_bfloat16*)wsb;          // region A (alias, p1 dead)
  float* p2  = (float*)(wsb + BYTE_B);                // region B
  float* h4  = (float*)(wsb + BYTE_B);                // region B (alias, p2 dead)
  float* p3  = (float*)(wsb + BYTE_C);
  float* dec = (float*)(wsb + BYTE_D);
  float* out = (float*)d_out;                         // OUTPUT IS FLOAT32

  // element offsets into f32 out: [out | mu | logvar | kld | z]
  const size_t off_z   = (size_t)out_size - 32768;
  const size_t off_kld = off_z - 256;
  const size_t off_lv  = off_kld - 32768;
  const size_t off_mu  = off_lv - 32768;

  k1_conv1_pool<<<dim3(BATCH, 10), 256, 0, stream>>>(x, w1, b1, p1);
  k2_conv2_pool<<<dim3(BATCH, 10), 256, 0, stream>>>(p1, w2, b2, p2);
  k3_conv3_pool<<<dim3(BATCH), 256, 0, stream>>>(p2, w3, b3, p3);
  k4_latent<<<dim3(BATCH), 64, 0, stream>>>(p3, eps, wmu, bmu, wlv, blv, wlin, blin,
                                            dec, out, off_mu, off_lv, off_kld, off_z);
  k5_inv1_conv4<<<dim3(BATCH), 256, 0, stream>>>(dec, wi1, bi1, w4, b4, h4);
  k6_inv2_conv5<<<dim3(BATCH, 5), 256, 0, stream>>>(h4, wi2, bi2, w5, b5, h5);
  k7_inv3_conv6<<<dim3(BATCH, 10), 256, 0, stream>>>(h5, wi3, bi3, w6, b6, out);
}